// Round 1
// 1333.781 us; speedup vs baseline: 1.1487x; 1.1487x over previous
//
#include <hip/hip_runtime.h>
#include <math.h>

#define N_NODES  2000000
#define N_GRAPHS 8192
#define CDIM     128
#define GPB      4          // graphs per block in fused kernel

// ---------------------------------------------------------------------------
// starts[g] = first row of graph g (batch is sorted ascending);
// starts[N_GRAPHS] = N_NODES.  O(N) boundary scan: thread i owns the
// boundary between batch[i] and batch[i+1].  Fully parallel (7813 blocks),
// replaces the latency-bound 32-block binary-search kernel.
// ---------------------------------------------------------------------------
__global__ __launch_bounds__(256) void starts_kernel(const int* __restrict__ batch,
                                                     int* __restrict__ starts) {
    int i = blockIdx.x * blockDim.x + threadIdx.x;
    if (i >= N_NODES) return;
    int b = batch[i];
    if (i == 0) {
        for (int g = 0; g <= b; ++g) starts[g] = 0;          // head (incl. empty leading graphs)
    }
    if (i == N_NODES - 1) {
        for (int g = b + 1; g <= N_GRAPHS; ++g) starts[g] = N_NODES;   // tail sentinel(s)
    } else {
        int bn = batch[i + 1];
        for (int g = b + 1; g <= bn; ++g) starts[g] = i + 1; // covers empty graphs in gaps too
    }
}

// ---------------------------------------------------------------------------
// Fused per-graph reduce (sum+max over a CONTIGUOUS row range — batch is
// sorted, so no atomics, no init, no per-row batch reads) + gated GEMM +
// sigmoid blend.  One block = GPB graphs; one wave handles one graph in the
// GEMM epilogue.
// Thread layout in the streaming phase: q = tid&31 (float4 column quad),
// rl = tid>>5 (8 row lanes), 2-deep unrolled loads for MLP.
// ---------------------------------------------------------------------------
__global__ __launch_bounds__(256) void fused_kernel(const float4* __restrict__ x4,
                                                    const int* __restrict__ starts,
                                                    const float* __restrict__ W,
                                                    const float* __restrict__ bias,
                                                    float* __restrict__ out) {
    __shared__ float mean_s[GPB][CDIM];
    __shared__ float maxx_s[GPB][CDIM];
    __shared__ float red_sum[4][CDIM];   // [wave][channel] cross-wave staging
    __shared__ float red_max[4][CDIM];

    const int tid  = threadIdx.x;
    const int q    = tid & 31;     // column quad (4 channels)
    const int rl   = tid >> 5;     // row lane 0..7
    const int wave = tid >> 6;     // 0..3
    const int lane = tid & 63;
    const int g0   = blockIdx.x * GPB;
    const float ninf = -__builtin_huge_valf();

    for (int gl = 0; gl < GPB; ++gl) {
        const int s0 = starts[g0 + gl];
        const int s1 = starts[g0 + gl + 1];

        float4 s = make_float4(0.f, 0.f, 0.f, 0.f);
        float4 m = make_float4(ninf, ninf, ninf, ninf);

        int r = s0 + rl;
        // 2-deep unroll: two independent 512B-wide row loads in flight/thread
        for (; r + 8 < s1; r += 16) {
            float4 v0 = x4[(size_t)r       * (CDIM / 4) + q];
            float4 v1 = x4[(size_t)(r + 8) * (CDIM / 4) + q];
            s.x += v0.x + v1.x; s.y += v0.y + v1.y;
            s.z += v0.z + v1.z; s.w += v0.w + v1.w;
            m.x = fmaxf(m.x, fmaxf(v0.x, v1.x));
            m.y = fmaxf(m.y, fmaxf(v0.y, v1.y));
            m.z = fmaxf(m.z, fmaxf(v0.z, v1.z));
            m.w = fmaxf(m.w, fmaxf(v0.w, v1.w));
        }
        if (r < s1) {
            float4 v = x4[(size_t)r * (CDIM / 4) + q];
            s.x += v.x; s.y += v.y; s.z += v.z; s.w += v.w;
            m.x = fmaxf(m.x, v.x); m.y = fmaxf(m.y, v.y);
            m.z = fmaxf(m.z, v.z); m.w = fmaxf(m.w, v.w);
        }

        // reduce the 2 row-lanes within each wave: lanes l <-> l^32 share q
        s.x += __shfl_xor(s.x, 32); s.y += __shfl_xor(s.y, 32);
        s.z += __shfl_xor(s.z, 32); s.w += __shfl_xor(s.w, 32);
        m.x = fmaxf(m.x, __shfl_xor(m.x, 32));
        m.y = fmaxf(m.y, __shfl_xor(m.y, 32));
        m.z = fmaxf(m.z, __shfl_xor(m.z, 32));
        m.w = fmaxf(m.w, __shfl_xor(m.w, 32));

        if (lane < 32) {
            *(float4*)&red_sum[wave][q * 4] = s;
            *(float4*)&red_max[wave][q * 4] = m;
        }
        __syncthreads();

        if (tid < CDIM) {
            float ssum = red_sum[0][tid] + red_sum[1][tid]
                       + red_sum[2][tid] + red_sum[3][tid];
            float smax = fmaxf(fmaxf(red_max[0][tid], red_max[1][tid]),
                               fmaxf(red_max[2][tid], red_max[3][tid]));
            int cnt = s1 - s0;
            float mv = 0.f, xv = 0.f;
            if (cnt > 0) {               // empty graph -> mean=0, max=0 (ref semantics)
                mv = ssum / (float)cnt;
                xv = smax;
            }
            mean_s[gl][tid] = mv;
            maxx_s[gl][tid] = xv;
        }
        __syncthreads();   // also protects red_* reuse next iteration
    }

    // ---- gated GEMM + blend: one graph per wave, 2 channels per thread ----
    const int j0 = (tid & 63) * 2;
    const int gw = wave;
    float acc0 = 0.f, acc1 = 0.f;

    // K = 0..127 : mean part
#pragma unroll 4
    for (int kq = 0; kq < CDIM / 4; ++kq) {
        int k = kq * 4;
        float2 w0 = *(const float2*)(W + (size_t)(k + 0) * CDIM + j0);
        float2 w1 = *(const float2*)(W + (size_t)(k + 1) * CDIM + j0);
        float2 w2 = *(const float2*)(W + (size_t)(k + 2) * CDIM + j0);
        float2 w3 = *(const float2*)(W + (size_t)(k + 3) * CDIM + j0);
        float4 mv = *(const float4*)&mean_s[gw][k];   // wave-uniform -> LDS broadcast
        acc0 += mv.x * w0.x + mv.y * w1.x + mv.z * w2.x + mv.w * w3.x;
        acc1 += mv.x * w0.y + mv.y * w1.y + mv.z * w2.y + mv.w * w3.y;
    }
    // K = 128..255 : max part
#pragma unroll 4
    for (int kq = 0; kq < CDIM / 4; ++kq) {
        int k = kq * 4;
        const float* Wr = W + (size_t)(CDIM + k) * CDIM + j0;
        float2 w0 = *(const float2*)(Wr + 0 * CDIM);
        float2 w1 = *(const float2*)(Wr + 1 * CDIM);
        float2 w2 = *(const float2*)(Wr + 2 * CDIM);
        float2 w3 = *(const float2*)(Wr + 3 * CDIM);
        float4 xv = *(const float4*)&maxx_s[gw][k];
        acc0 += xv.x * w0.x + xv.y * w1.x + xv.z * w2.x + xv.w * w3.x;
        acc1 += xv.x * w0.y + xv.y * w1.y + xv.z * w2.y + xv.w * w3.y;
    }

    float2 bb = *(const float2*)(bias + j0);
    float z0 = acc0 + bb.x;
    float z1 = acc1 + bb.y;
    float a0 = 1.0f / (1.0f + expf(-z0));
    float a1 = 1.0f / (1.0f + expf(-z1));
    float m0 = mean_s[gw][j0 + 0];
    float m1 = mean_s[gw][j0 + 1];
    float x0 = maxx_s[gw][j0 + 0];
    float x1 = maxx_s[gw][j0 + 1];
    float2 o;
    o.x = a0 * m0 + (1.0f - a0) * x0;
    o.y = a1 * m1 + (1.0f - a1) * x1;
    *(float2*)(out + (size_t)(g0 + gw) * CDIM + j0) = o;
}

extern "C" void kernel_launch(void* const* d_in, const int* in_sizes, int n_in,
                              void* d_out, int out_size, void* d_ws, size_t ws_size,
                              hipStream_t stream) {
    const float* x     = (const float*)d_in[0];
    const int*   batch = (const int*)d_in[1];
    const float* W     = (const float*)d_in[2];
    const float* bias  = (const float*)d_in[3];
    float*       out   = (float*)d_out;

    // workspace: starts [N_GRAPHS+1] i32 (fully rewritten every launch, so
    // harness re-poisoning of d_ws is harmless)
    int* starts = (int*)d_ws;

    // 1) segment start offsets via O(N) boundary scan (~4 us)
    starts_kernel<<<(N_NODES + 255) / 256, 256, 0, stream>>>(batch, starts);

    // 2) fused contiguous-range reduce + gated GEMM + blend (atomic-free)
    fused_kernel<<<N_GRAPHS / GPB, 256, 0, stream>>>((const float4*)x, starts,
                                                     W, bias, out);
}